// Round 4
// baseline (372.600 us; speedup 1.0000x reference)
//
#include <hip/hip_runtime.h>
#include <hip/hip_bf16.h>

// ---------------- types ----------------
typedef __bf16 bf16x8 __attribute__((ext_vector_type(8)));
typedef float  f32x4  __attribute__((ext_vector_type(4)));

#define GM 16384
#define GN 2048
#define GK 3072        // logical K: hi*hi + hi*lo + lo*hi
#define PK 2048        // physical packed width: [hi | lo]
#define DIM 1024
#define NSPLIT 1023
#define NLEAF 1024

#define BM 256
#define BN 256
#define BK 32
#define NKT (GK / BK)   // 96 logical K-tiles

// ---------------- helpers ----------------
__device__ __forceinline__ void gload_lds16(const void* g, void* lds) {
    __builtin_amdgcn_global_load_lds(
        (const __attribute__((address_space(1))) void*)g,
        (__attribute__((address_space(3))) void*)lds, 16, 0, 0);
}

// ---------------- pack kernels ----------------
// A' physical layout: [hi(1024) | lo(1024)], row-major (GM x PK) bf16.
// Logical A k-tiles: 0..31 -> hi, 32..63 -> hi (again), 64..95 -> lo.
__global__ void pack_A(const float* __restrict__ x, __bf16* __restrict__ Ap) {
    size_t tid = (size_t)blockIdx.x * 256 + threadIdx.x;
    size_t idx = tid * 8;
    int m = (int)(idx >> 10);
    int k = (int)(idx & 1023);
    float4 v0 = *(const float4*)(x + idx);
    float4 v1 = *(const float4*)(x + idx + 4);
    float vs[8] = {v0.x, v0.y, v0.z, v0.w, v1.x, v1.y, v1.z, v1.w};
    bf16x8 hi, lo;
#pragma unroll
    for (int j = 0; j < 8; ++j) {
        __bf16 h = (__bf16)vs[j];
        hi[j] = h;
        lo[j] = (__bf16)(vs[j] - (float)h);
    }
    __bf16* base = Ap + (size_t)m * PK + k;
    *(bf16x8*)(base)        = hi;
    *(bf16x8*)(base + 1024) = lo;
}

// B' rows: 0..1022 = W_split, 1023..2046 = W_leaf, 2047 = zeros.
// B' physical layout: [hi(1024) | lo(1024)], row-major (GN x PK).
// Logical B k-tiles: 0..31 -> hi, 32..63 -> lo, 64..95 -> hi (again).
__global__ void pack_B(const float* __restrict__ Ws, const float* __restrict__ Wl,
                       __bf16* __restrict__ Bp) {
    size_t tid = (size_t)blockIdx.x * 256 + threadIdx.x;
    size_t idx = tid * 8;
    int n = (int)(idx >> 10);
    int k = (int)(idx & 1023);
    float vs[8];
    if (n < NSPLIT) {
        const float* s = Ws + (size_t)n * DIM + k;
        float4 v0 = *(const float4*)(s);
        float4 v1 = *(const float4*)(s + 4);
        vs[0]=v0.x; vs[1]=v0.y; vs[2]=v0.z; vs[3]=v0.w;
        vs[4]=v1.x; vs[5]=v1.y; vs[6]=v1.z; vs[7]=v1.w;
    } else if (n < NSPLIT + NLEAF) {
        const float* s = Wl + (size_t)(n - NSPLIT) * DIM + k;
        float4 v0 = *(const float4*)(s);
        float4 v1 = *(const float4*)(s + 4);
        vs[0]=v0.x; vs[1]=v0.y; vs[2]=v0.z; vs[3]=v0.w;
        vs[4]=v1.x; vs[5]=v1.y; vs[6]=v1.z; vs[7]=v1.w;
    } else {
#pragma unroll
        for (int j = 0; j < 8; ++j) vs[j] = 0.0f;
    }
    bf16x8 hi, lo;
#pragma unroll
    for (int j = 0; j < 8; ++j) {
        __bf16 h = (__bf16)vs[j];
        hi[j] = h;
        lo[j] = (__bf16)(vs[j] - (float)h);
    }
    __bf16* base = Bp + (size_t)n * PK + k;
    *(bf16x8*)(base)        = hi;
    *(bf16x8*)(base + 1024) = lo;
}

// ---------------- GEMM: 256x256, BK=32, 4-slot ring, 4-phase interleave ----
// 8 waves (2m x 4n), per-wave 128x64 output (8x4 frags). Ring + counted-vmcnt
// invariants identical to the round-3 kernel (hardware-validated): staging of
// tile t+3 targets slot (t-1)&3 (freed), end-of-K-step vmcnt(8) retires
// exactly tile t+1's 4 loads before its slot is read.
// NEW: each K-step split into 4 phases {ds_read subtile; 1 stage-gload;
// barrier; setprio(1); 8 MFMA; setprio(0); barrier} so ds_read latency of
// phase p overlaps MFMA of other waves and the compiler cannot collapse the
// schedule into read-all-then-MFMA-all (T3+T4+T5, m201/m218 levers).
__global__ __launch_bounds__(512, 2) void gemm_kernel(const __bf16* __restrict__ A,
                                                      const __bf16* __restrict__ B,
                                                      const float* __restrict__ bs,
                                                      const float* __restrict__ bl,
                                                      float* __restrict__ C) {
    __shared__ __bf16 lds[4][2][BM * BK];   // 4 ring slots x {A,B} x 16 KiB

    const int t    = threadIdx.x;
    const int wave = t >> 6;
    const int lane = t & 63;
    const int wr   = wave >> 2;   // 0..1
    const int wc   = wave & 3;    // 0..3
    const int r15  = lane & 15;
    const int kc   = lane >> 4;

    // XCD-chunked block swizzle (512 = 8 xcds x 64)
    int g    = blockIdx.x;
    int tile = (g & 7) * 64 + (g >> 3);
    int mt   = tile >> 3;
    int nt   = tile & 7;

    const __bf16* Abase = A + (size_t)mt * BM * PK;
    const __bf16* Bbase = B + (size_t)nt * BN * PK;

    // staging coords: chunk ca = {t, 512+t}; r = ca>>2; swizzled col chunk
    const int ca0 = t, ca1 = 512 + t;
    const int rA0 = ca0 >> 2, cs0 = (ca0 & 3) ^ ((rA0 >> 1) & 3);
    const int rA1 = ca1 >> 2, cs1 = (ca1 & 3) ^ ((rA1 >> 1) & 3);
    const __bf16* gA0 = Abase + (size_t)rA0 * PK + cs0 * 8;
    const __bf16* gA1 = Abase + (size_t)rA1 * PK + cs1 * 8;
    const __bf16* gB0 = Bbase + (size_t)rA0 * PK + cs0 * 8;
    const __bf16* gB1 = Bbase + (size_t)rA1 * PK + cs1 * 8;
    const int dst0 = (wave * 64) * 8;
    const int dst1 = (512 + wave * 64) * 8;

    // logical k-tile -> physical element offset
#define KOFF_A(TT) ((((TT) < 32) ? (TT) : (TT) - 32) * 32)
#define KOFF_B(TT) ((((TT) < 64) ? (TT) : (TT) - 64) * 32)

    f32x4 acc[8][4];
#pragma unroll
    for (int m = 0; m < 8; ++m)
#pragma unroll
        for (int n = 0; n < 4; ++n) acc[m][n] = (f32x4){0.f, 0.f, 0.f, 0.f};

    // prologue: stage tiles 0,1,2 -> wait tile 0 (oldest 4 of 12)
#pragma unroll
    for (int tp = 0; tp < 3; ++tp) {
        gload_lds16(gA0 + KOFF_A(tp), &lds[tp][0][dst0]);
        gload_lds16(gA1 + KOFF_A(tp), &lds[tp][0][dst1]);
        gload_lds16(gB0 + KOFF_B(tp), &lds[tp][1][dst0]);
        gload_lds16(gB1 + KOFF_B(tp), &lds[tp][1][dst1]);
    }
    asm volatile("s_waitcnt vmcnt(8)" ::: "memory");
    __builtin_amdgcn_sched_barrier(0);
    __builtin_amdgcn_s_barrier();
    __builtin_amdgcn_sched_barrier(0);

#define PHASE_SYNC_PRE()  do {                        \
        __builtin_amdgcn_sched_barrier(0);            \
        __builtin_amdgcn_s_barrier();                 \
        __builtin_amdgcn_sched_barrier(0);            \
        __builtin_amdgcn_s_setprio(1);                \
    } while (0)
#define PHASE_SYNC_POST() do {                        \
        __builtin_amdgcn_s_setprio(0);                \
        __builtin_amdgcn_sched_barrier(0);            \
        __builtin_amdgcn_s_barrier();                 \
        __builtin_amdgcn_sched_barrier(0);            \
    } while (0)

#pragma unroll 1
    for (int tt = 0; tt < NKT; ++tt) {
        const int rb  = tt & 3;
        const int rb3 = (tt + 3) & 3;
        const bool st = (tt + 3 < NKT);
        const int kA3 = KOFF_A(tt + 3);
        const int kB3 = KOFF_B(tt + 3);
        const __bf16* As_ = &lds[rb][0][0];
        const __bf16* Bs_ = &lds[rb][1][0];

        bf16x8 aL[4], aH[4], b0[2], b1[2];

        // ---- phase 0: read aL + b0, stage A-half0(t+3), MFMA m0-3 x n0-1 --
#pragma unroll
        for (int m = 0; m < 4; ++m) {
            int R = wr * 128 + m * 16 + r15;
            aL[m] = *(const bf16x8*)&As_[R * 32 + ((kc ^ ((R >> 1) & 3)) * 8)];
        }
#pragma unroll
        for (int n = 0; n < 2; ++n) {
            int R = wc * 64 + n * 16 + r15;
            b0[n] = *(const bf16x8*)&Bs_[R * 32 + ((kc ^ ((R >> 1) & 3)) * 8)];
        }
        if (st) gload_lds16(gA0 + kA3, &lds[rb3][0][dst0]);
        PHASE_SYNC_PRE();
#pragma unroll
        for (int m = 0; m < 4; ++m)
#pragma unroll
            for (int n = 0; n < 2; ++n)
                acc[m][n] = __builtin_amdgcn_mfma_f32_16x16x32_bf16(
                    aL[m], b0[n], acc[m][n], 0, 0, 0);
        PHASE_SYNC_POST();

        // ---- phase 1: read b1, stage A-half1(t+3), MFMA m0-3 x n2-3 -------
#pragma unroll
        for (int n = 0; n < 2; ++n) {
            int R = wc * 64 + (n + 2) * 16 + r15;
            b1[n] = *(const bf16x8*)&Bs_[R * 32 + ((kc ^ ((R >> 1) & 3)) * 8)];
        }
        if (st) gload_lds16(gA1 + kA3, &lds[rb3][0][dst1]);
        PHASE_SYNC_PRE();
#pragma unroll
        for (int m = 0; m < 4; ++m)
#pragma unroll
            for (int n = 0; n < 2; ++n)
                acc[m][n + 2] = __builtin_amdgcn_mfma_f32_16x16x32_bf16(
                    aL[m], b1[n], acc[m][n + 2], 0, 0, 0);
        PHASE_SYNC_POST();

        // ---- phase 2: read aH, stage B-half0(t+3), MFMA m4-7 x n2-3 -------
#pragma unroll
        for (int m = 0; m < 4; ++m) {
            int R = wr * 128 + (m + 4) * 16 + r15;
            aH[m] = *(const bf16x8*)&As_[R * 32 + ((kc ^ ((R >> 1) & 3)) * 8)];
        }
        if (st) gload_lds16(gB0 + kB3, &lds[rb3][1][dst0]);
        PHASE_SYNC_PRE();
#pragma unroll
        for (int m = 0; m < 4; ++m)
#pragma unroll
            for (int n = 0; n < 2; ++n)
                acc[m + 4][n + 2] = __builtin_amdgcn_mfma_f32_16x16x32_bf16(
                    aH[m], b1[n], acc[m + 4][n + 2], 0, 0, 0);
        PHASE_SYNC_POST();

        // ---- phase 3: no reads, stage B-half1(t+3), vmcnt, MFMA m4-7 x n0-1
        if (st) gload_lds16(gB1 + kB3, &lds[rb3][1][dst1]);
        if (st)                  asm volatile("s_waitcnt vmcnt(8)" ::: "memory");
        else if (tt + 3 == NKT)  asm volatile("s_waitcnt vmcnt(4)" ::: "memory");
        else if (tt + 2 == NKT)  asm volatile("s_waitcnt vmcnt(0)" ::: "memory");
        PHASE_SYNC_PRE();
#pragma unroll
        for (int m = 0; m < 4; ++m)
#pragma unroll
            for (int n = 0; n < 2; ++n)
                acc[m + 4][n] = __builtin_amdgcn_mfma_f32_16x16x32_bf16(
                    aH[m], b0[n], acc[m + 4][n], 0, 0, 0);
        PHASE_SYNC_POST();
    }
#undef KOFF_A
#undef KOFF_B
#undef PHASE_SYNC_PRE
#undef PHASE_SYNC_POST

    // epilogue: fused bias + sigmoid (split cols) / bias (leaf cols)
    const int r0 = mt * BM + wr * 128 + (lane >> 4) * 4;
    const int c0 = nt * BN + wc * 64 + r15;
#pragma unroll
    for (int m = 0; m < 8; ++m)
#pragma unroll
        for (int n = 0; n < 4; ++n) {
            int col = c0 + n * 16;
#pragma unroll
            for (int j = 0; j < 4; ++j) {
                float v = acc[m][n][j];
                float o;
                if (col < NSPLIT) {
                    v += bs[col];
                    o = 1.0f / (1.0f + __expf(-v));
                } else if (col < NSPLIT + NLEAF) {
                    o = v + bl[col - NSPLIT];
                } else {
                    o = 0.0f;
                }
                C[(size_t)(r0 + m * 16 + j) * GN + col] = o;
            }
        }
}

// ---------------- routing: pure product walk -------------------------------
__global__ __launch_bounds__(256) void routing_kernel(const float* __restrict__ S,
                                                      float* __restrict__ out) {
    __shared__ float rowbuf[4][2048];
    const int wave = threadIdx.x >> 6;
    const int lane = threadIdx.x & 63;
    const int b    = blockIdx.x * 4 + wave;

    const float* srow = S + (size_t)b * GN;
#pragma unroll
    for (int i = 0; i < 8; ++i) {
        int idx = i * 64 + lane;
        *(float4*)&rowbuf[wave][idx * 4] = ((const float4*)srow)[idx];
    }
    __syncthreads();

    float acc = 0.0f;
#pragma unroll
    for (int j = 0; j < 16; ++j) {
        int l = j * 64 + lane;
        float w = 1.0f;
        int off = 0;
#pragma unroll
        for (int d = 0; d < 10; ++d) {
            int node = off + (l >> (10 - d));
            float p  = rowbuf[wave][node];
            int bit  = (l >> (9 - d)) & 1;
            w *= bit ? p : (1.0f - p);
            off += (1 << d);
        }
        acc += w * rowbuf[wave][NSPLIT + l];
    }
#pragma unroll
    for (int s = 32; s > 0; s >>= 1) acc += __shfl_down(acc, s, 64);
    if (lane == 0) out[b] = acc;
}

// ---------------- launcher ----------------
extern "C" void kernel_launch(void* const* d_in, const int* in_sizes, int n_in,
                              void* d_out, int out_size, void* d_ws, size_t ws_size,
                              hipStream_t stream) {
    const float* x      = (const float*)d_in[0];
    const float* Wsplit = (const float*)d_in[1];
    const float* bsplit = (const float*)d_in[2];
    const float* Wleaf  = (const float*)d_in[3];
    const float* bleaf  = (const float*)d_in[4];
    float* out          = (float*)d_out;

    char* ws = (char*)d_ws;
    __bf16* Ap = (__bf16*)ws;                                   // 64 MiB
    __bf16* Bp = (__bf16*)(ws + (size_t)GM * PK * 2);           // 8 MiB
    float*  S  = (float*)(ws + (size_t)GM * PK * 2 + (size_t)GN * PK * 2); // 128 MiB

    pack_A<<<(GM * DIM / 8) / 256, 256, 0, stream>>>(x, Ap);
    pack_B<<<(GN * DIM / 8) / 256, 256, 0, stream>>>(Wsplit, Wleaf, Bp);

    gemm_kernel<<<512, 512, 0, stream>>>(Ap, Bp, bsplit, bleaf, S);

    routing_kernel<<<GM / 4, 256, 0, stream>>>(S, out);
}

// Round 6
// 342.849 us; speedup vs baseline: 1.0868x; 1.0868x over previous
//
#include <hip/hip_runtime.h>
#include <hip/hip_bf16.h>

// ---------------- types ----------------
typedef __bf16 bf16x8 __attribute__((ext_vector_type(8)));
typedef float  f32x4  __attribute__((ext_vector_type(4)));

#define GM 16384
#define GN 2048
#define GK 3072        // logical K: hi*hi + hi*lo + lo*hi
#define PK 2048        // physical packed width: [hi | lo]
#define DIM 1024
#define NSPLIT 1023
#define NLEAF 1024

#define BM 256
#define BN 256
#define BK 64
#define NT 48          // logical K-tiles of 64
#define NIT 24         // iterations, 2 K-tiles each

// ---------------- helpers ----------------
__device__ __forceinline__ void gload_lds16(const void* g, void* lds) {
    __builtin_amdgcn_global_load_lds(
        (const __attribute__((address_space(1))) void*)g,
        (__attribute__((address_space(3))) void*)lds, 16, 0, 0);
}

// ---------------- pack kernels (proven rounds 3-4) ----------------
// A' physical [hi|lo]; logical A k-tiles: 0-15 hi, 16-31 hi, 32-47 lo.
__global__ void pack_A(const float* __restrict__ x, __bf16* __restrict__ Ap) {
    size_t tid = (size_t)blockIdx.x * 256 + threadIdx.x;
    size_t idx = tid * 8;
    int m = (int)(idx >> 10);
    int k = (int)(idx & 1023);
    float4 v0 = *(const float4*)(x + idx);
    float4 v1 = *(const float4*)(x + idx + 4);
    float vs[8] = {v0.x, v0.y, v0.z, v0.w, v1.x, v1.y, v1.z, v1.w};
    bf16x8 hi, lo;
#pragma unroll
    for (int j = 0; j < 8; ++j) {
        __bf16 h = (__bf16)vs[j];
        hi[j] = h;
        lo[j] = (__bf16)(vs[j] - (float)h);
    }
    __bf16* base = Ap + (size_t)m * PK + k;
    *(bf16x8*)(base)        = hi;
    *(bf16x8*)(base + 1024) = lo;
}

// B' rows: 0-1022 W_split, 1023-2046 W_leaf, 2047 zeros; physical [hi|lo].
// Logical B k-tiles: 0-15 hi, 16-31 lo, 32-47 hi.
__global__ void pack_B(const float* __restrict__ Ws, const float* __restrict__ Wl,
                       __bf16* __restrict__ Bp) {
    size_t tid = (size_t)blockIdx.x * 256 + threadIdx.x;
    size_t idx = tid * 8;
    int n = (int)(idx >> 10);
    int k = (int)(idx & 1023);
    float vs[8];
    if (n < NSPLIT) {
        const float* s = Ws + (size_t)n * DIM + k;
        float4 v0 = *(const float4*)(s);
        float4 v1 = *(const float4*)(s + 4);
        vs[0]=v0.x; vs[1]=v0.y; vs[2]=v0.z; vs[3]=v0.w;
        vs[4]=v1.x; vs[5]=v1.y; vs[6]=v1.z; vs[7]=v1.w;
    } else if (n < NSPLIT + NLEAF) {
        const float* s = Wl + (size_t)(n - NSPLIT) * DIM + k;
        float4 v0 = *(const float4*)(s);
        float4 v1 = *(const float4*)(s + 4);
        vs[0]=v0.x; vs[1]=v0.y; vs[2]=v0.z; vs[3]=v0.w;
        vs[4]=v1.x; vs[5]=v1.y; vs[6]=v1.z; vs[7]=v1.w;
    } else {
#pragma unroll
        for (int j = 0; j < 8; ++j) vs[j] = 0.0f;
    }
    bf16x8 hi, lo;
#pragma unroll
    for (int j = 0; j < 8; ++j) {
        __bf16 h = (__bf16)vs[j];
        hi[j] = h;
        lo[j] = (__bf16)(vs[j] - (float)h);
    }
    __bf16* base = Bp + (size_t)n * PK + k;
    *(bf16x8*)(base)        = hi;
    *(bf16x8*)(base + 1024) = lo;
}

// ---------------- GEMM: 256x256, BK=64, 8-phase template (m201 port) ------
// 8 waves (2m x 4n), per-wave 128x64 (8x4 frags of 16x16x32). LDS: buffer by
// K-tile parity: lds[p][A/B][256*64]. Stage schedule (half-tile per phase),
// derived from last-read times so every LDS write is >=1 barrier after the
// last read of that region (WAR-free):
//   ph1:A1(V) ph2:B1(V) ph3:B0(T2) ph4:A0(T2) ph5:A1(T2) ph6:B1(T2)
//   ph7:B0(T3) ph8:A0(T3)        (V=2i+1, T2=2i+2, T3=2i+3)
// vmcnt(4) at ph4 retires tile-V's 4 half-tiles (8 loads) before ph5 reads V;
// vmcnt(4) at ph8 retires tile-T2's 8 loads before next-iter ph1 reads T2.
// Swizzle: LDS chunk j of row R holds global chunk j^(R&7) (both-sides XOR).
__global__ __launch_bounds__(512, 2) void gemm_kernel(const __bf16* __restrict__ A,
                                                      const __bf16* __restrict__ B,
                                                      const float* __restrict__ bs,
                                                      const float* __restrict__ bl,
                                                      float* __restrict__ C) {
    __shared__ __bf16 lds[2][2][BM * BK];   // [parity][A/B] 32 KiB each = 128 KiB

    const int t    = threadIdx.x;
    const int wave = t >> 6;
    const int lane = t & 63;
    const int wr   = wave >> 2;   // 0..1
    const int wc   = wave & 3;    // 0..3
    const int r15  = lane & 15;
    const int kc4  = lane >> 4;   // 0..3

    // XCD-chunked block swizzle (512 = 8 xcds x 64)
    int g    = blockIdx.x;
    int tile = (g & 7) * 64 + (g >> 3);
    int mt   = tile >> 3;
    int nt   = tile & 7;

    const __bf16* Abase = A + (size_t)mt * BM * PK;
    const __bf16* Bbase = B + (size_t)nt * BN * PK;

    // staging: half-tile = 128 rows x 64 cols = 1024 16B-chunks / 512 thr.
    const int ca0 = t, ca1 = 512 + t;
    const int r0s = ca0 >> 3, c0s = (ca0 & 7) ^ (r0s & 7);
    const int r1s = ca1 >> 3, c1s = (ca1 & 7) ^ (r1s & 7);
    const __bf16* gA0 = Abase + (size_t)r0s * PK + c0s * 8;
    const __bf16* gA1 = Abase + (size_t)r1s * PK + c1s * 8;
    const __bf16* gB0 = Bbase + (size_t)r0s * PK + c0s * 8;
    const __bf16* gB1 = Bbase + (size_t)r1s * PK + c1s * 8;
    const int de0 = (wave * 64) * 8;           // LDS element offset, load 0
    const int de1 = (512 + wave * 64) * 8;     // load 1

    // logical k-tile -> physical element offset
#define KOA(T) (((T) < 16) ? (T) * 64 : (T) * 64 - 1024)
#define KOB(T) (((T) < 32) ? (T) * 64 : (T) * 64 - 2048)

#define STG_A(T, h) do { int ko_ = KOA(T); size_t hb_ = (size_t)(h) * 128 * PK;   \
        gload_lds16(gA0 + hb_ + ko_, &lds[(T) & 1][0][(h) * 8192 + de0]);          \
        gload_lds16(gA1 + hb_ + ko_, &lds[(T) & 1][0][(h) * 8192 + de1]); } while (0)
#define STG_B(T, h) do { int ko_ = KOB(T); size_t hb_ = (size_t)(h) * 128 * PK;   \
        gload_lds16(gB0 + hb_ + ko_, &lds[(T) & 1][1][(h) * 8192 + de0]);          \
        gload_lds16(gB1 + hb_ + ko_, &lds[(T) & 1][1][(h) * 8192 + de1]); } while (0)

    // fragment reads (both-sides swizzle involution)
#define RD_A(dst, buf, m, ks) do { int R_ = wr * 128 + (m) * 16 + r15;            \
        dst = *(const bf16x8*)&lds[buf][0][R_ * 64 + ((((ks) * 4 + kc4) ^ (R_ & 7)) * 8)]; } while (0)
#define RD_B(dst, buf, n, ks) do { int R_ = wc * 64 + (n) * 16 + r15;             \
        dst = *(const bf16x8*)&lds[buf][1][R_ * 64 + ((((ks) * 4 + kc4) ^ (R_ & 7)) * 8)]; } while (0)

#define SYNC_PRE()  do { __builtin_amdgcn_s_barrier();                            \
        asm volatile("s_waitcnt lgkmcnt(0)" ::: "memory");                        \
        __builtin_amdgcn_sched_barrier(0);                                        \
        __builtin_amdgcn_s_setprio(1); } while (0)
#define SYNC_POST() do { __builtin_amdgcn_s_setprio(0);                           \
        __builtin_amdgcn_s_barrier(); } while (0)

    f32x4 acc[8][4];
#pragma unroll
    for (int m = 0; m < 8; ++m)
#pragma unroll
        for (int n = 0; n < 4; ++n) acc[m][n] = (f32x4){0.f, 0.f, 0.f, 0.f};

    // prologue: tile0 full + tile1 {A0,B0} = 12 loads; retire tile0's 8.
    STG_A(0, 0); STG_A(0, 1); STG_B(0, 0); STG_B(0, 1);
    STG_A(1, 0); STG_B(1, 0);
    asm volatile("s_waitcnt vmcnt(4)" ::: "memory");
    __builtin_amdgcn_s_barrier();

#pragma unroll 1
    for (int i = 0; i < NIT; ++i) {
        const int V = 2 * i + 1, T2 = 2 * i + 2, T3 = 2 * i + 3;
        bf16x8 aL[4][2], aH[4][2], b01[2][2], b23[2][2];

        // ===== phase 1: tile U(buf0), m0-3 x n0-1 (12 ds_reads) =====
#pragma unroll
        for (int m = 0; m < 4; ++m) { RD_A(aL[m][0], 0, m, 0); RD_A(aL[m][1], 0, m, 1); }
#pragma unroll
        for (int n = 0; n < 2; ++n) { RD_B(b01[n][0], 0, n, 0); RD_B(b01[n][1], 0, n, 1); }
        STG_A(V, 1);
        asm volatile("s_waitcnt lgkmcnt(8)" ::: "memory");
        SYNC_PRE();
#pragma unroll
        for (int m = 0; m < 4; ++m)
#pragma unroll
            for (int n = 0; n < 2; ++n) {
                acc[m][n] = __builtin_amdgcn_mfma_f32_16x16x32_bf16(aL[m][0], b01[n][0], acc[m][n], 0, 0, 0);
                acc[m][n] = __builtin_amdgcn_mfma_f32_16x16x32_bf16(aL[m][1], b01[n][1], acc[m][n], 0, 0, 0);
            }
        SYNC_POST();

        // ===== phase 2: m0-3 x n2-3 (4 ds_reads) =====
#pragma unroll
        for (int n = 0; n < 2; ++n) { RD_B(b23[n][0], 0, n + 2, 0); RD_B(b23[n][1], 0, n + 2, 1); }
        STG_B(V, 1);
        SYNC_PRE();
#pragma unroll
        for (int m = 0; m < 4; ++m)
#pragma unroll
            for (int n = 0; n < 2; ++n) {
                acc[m][n + 2] = __builtin_amdgcn_mfma_f32_16x16x32_bf16(aL[m][0], b23[n][0], acc[m][n + 2], 0, 0, 0);
                acc[m][n + 2] = __builtin_amdgcn_mfma_f32_16x16x32_bf16(aL[m][1], b23[n][1], acc[m][n + 2], 0, 0, 0);
            }
        SYNC_POST();

        // ===== phase 3: m4-7 x n2-3 (8 ds_reads) =====
#pragma unroll
        for (int m = 0; m < 4; ++m) { RD_A(aH[m][0], 0, m + 4, 0); RD_A(aH[m][1], 0, m + 4, 1); }
        if (T2 < NT) STG_B(T2, 0);
        SYNC_PRE();
#pragma unroll
        for (int m = 0; m < 4; ++m)
#pragma unroll
            for (int n = 0; n < 2; ++n) {
                acc[m + 4][n + 2] = __builtin_amdgcn_mfma_f32_16x16x32_bf16(aH[m][0], b23[n][0], acc[m + 4][n + 2], 0, 0, 0);
                acc[m + 4][n + 2] = __builtin_amdgcn_mfma_f32_16x16x32_bf16(aH[m][1], b23[n][1], acc[m + 4][n + 2], 0, 0, 0);
            }
        SYNC_POST();

        // ===== phase 4: m4-7 x n0-1 (0 reads) + vmcnt gate =====
        if (T2 < NT) {
            STG_A(T2, 0);
            asm volatile("s_waitcnt vmcnt(4)" ::: "memory");
        } else {
            asm volatile("s_waitcnt vmcnt(0)" ::: "memory");
        }
        SYNC_PRE();
#pragma unroll
        for (int m = 0; m < 4; ++m)
#pragma unroll
            for (int n = 0; n < 2; ++n) {
                acc[m + 4][n] = __builtin_amdgcn_mfma_f32_16x16x32_bf16(aH[m][0], b01[n][0], acc[m + 4][n], 0, 0, 0);
                acc[m + 4][n] = __builtin_amdgcn_mfma_f32_16x16x32_bf16(aH[m][1], b01[n][1], acc[m + 4][n], 0, 0, 0);
            }
        SYNC_POST();

        // ===== phase 5: tile V(buf1), m0-3 x n0-1 (12 ds_reads) =====
#pragma unroll
        for (int m = 0; m < 4; ++m) { RD_A(aL[m][0], 1, m, 0); RD_A(aL[m][1], 1, m, 1); }
#pragma unroll
        for (int n = 0; n < 2; ++n) { RD_B(b01[n][0], 1, n, 0); RD_B(b01[n][1], 1, n, 1); }
        if (T2 < NT) STG_A(T2, 1);
        asm volatile("s_waitcnt lgkmcnt(8)" ::: "memory");
        SYNC_PRE();
#pragma unroll
        for (int m = 0; m < 4; ++m)
#pragma unroll
            for (int n = 0; n < 2; ++n) {
                acc[m][n] = __builtin_amdgcn_mfma_f32_16x16x32_bf16(aL[m][0], b01[n][0], acc[m][n], 0, 0, 0);
                acc[m][n] = __builtin_amdgcn_mfma_f32_16x16x32_bf16(aL[m][1], b01[n][1], acc[m][n], 0, 0, 0);
            }
        SYNC_POST();

        // ===== phase 6: m0-3 x n2-3 (4 ds_reads) =====
#pragma unroll
        for (int n = 0; n < 2; ++n) { RD_B(b23[n][0], 1, n + 2, 0); RD_B(b23[n][1], 1, n + 2, 1); }
        if (T2 < NT) STG_B(T2, 1);
        SYNC_PRE();
#pragma unroll
        for (int m = 0; m < 4; ++m)
#pragma unroll
            for (int n = 0; n < 2; ++n) {
                acc[m][n + 2] = __builtin_amdgcn_mfma_f32_16x16x32_bf16(aL[m][0], b23[n][0], acc[m][n + 2], 0, 0, 0);
                acc[m][n + 2] = __builtin_amdgcn_mfma_f32_16x16x32_bf16(aL[m][1], b23[n][1], acc[m][n + 2], 0, 0, 0);
            }
        SYNC_POST();

        // ===== phase 7: m4-7 x n2-3 (8 ds_reads) =====
#pragma unroll
        for (int m = 0; m < 4; ++m) { RD_A(aH[m][0], 1, m + 4, 0); RD_A(aH[m][1], 1, m + 4, 1); }
        if (T3 < NT) STG_B(T3, 0);
        SYNC_PRE();
#pragma unroll
        for (int m = 0; m < 4; ++m)
#pragma unroll
            for (int n = 0; n < 2; ++n) {
                acc[m + 4][n + 2] = __builtin_amdgcn_mfma_f32_16x16x32_bf16(aH[m][0], b23[n][0], acc[m + 4][n + 2], 0, 0, 0);
                acc[m + 4][n + 2] = __builtin_amdgcn_mfma_f32_16x16x32_bf16(aH[m][1], b23[n][1], acc[m + 4][n + 2], 0, 0, 0);
            }
        SYNC_POST();

        // ===== phase 8: m4-7 x n0-1 (0 reads) + vmcnt gate =====
        if (T3 < NT) {
            STG_A(T3, 0);
            asm volatile("s_waitcnt vmcnt(4)" ::: "memory");
        } else {
            asm volatile("s_waitcnt vmcnt(0)" ::: "memory");
        }
        SYNC_PRE();
#pragma unroll
        for (int m = 0; m < 4; ++m)
#pragma unroll
            for (int n = 0; n < 2; ++n) {
                acc[m + 4][n] = __builtin_amdgcn_mfma_f32_16x16x32_bf16(aH[m][0], b01[n][0], acc[m + 4][n], 0, 0, 0);
                acc[m + 4][n] = __builtin_amdgcn_mfma_f32_16x16x32_bf16(aH[m][1], b01[n][1], acc[m + 4][n], 0, 0, 0);
            }
        SYNC_POST();
    }
#undef KOA
#undef KOB
#undef STG_A
#undef STG_B
#undef RD_A
#undef RD_B
#undef SYNC_PRE
#undef SYNC_POST

    // epilogue: fused bias + sigmoid (split cols) / bias (leaf cols)
    const int r0 = mt * BM + wr * 128 + (lane >> 4) * 4;
    const int c0 = nt * BN + wc * 64 + r15;
#pragma unroll
    for (int m = 0; m < 8; ++m)
#pragma unroll
        for (int n = 0; n < 4; ++n) {
            int col = c0 + n * 16;
#pragma unroll
            for (int j = 0; j < 4; ++j) {
                float v = acc[m][n][j];
                float o;
                if (col < NSPLIT) {
                    v += bs[col];
                    o = 1.0f / (1.0f + __expf(-v));
                } else if (col < NSPLIT + NLEAF) {
                    o = v + bl[col - NSPLIT];
                } else {
                    o = 0.0f;
                }
                C[(size_t)(r0 + m * 16 + j) * GN + col] = o;
            }
        }
}

// ---------------- routing: pure product walk (proven rounds 3-4) ----------
__global__ __launch_bounds__(256) void routing_kernel(const float* __restrict__ S,
                                                      float* __restrict__ out) {
    __shared__ float rowbuf[4][2048];
    const int wave = threadIdx.x >> 6;
    const int lane = threadIdx.x & 63;
    const int b    = blockIdx.x * 4 + wave;

    const float* srow = S + (size_t)b * GN;
#pragma unroll
    for (int i = 0; i < 8; ++i) {
        int idx = i * 64 + lane;
        *(float4*)&rowbuf[wave][idx * 4] = ((const float4*)srow)[idx];
    }
    __syncthreads();

    float acc = 0.0f;
#pragma unroll
    for (int j = 0; j < 16; ++j) {
        int l = j * 64 + lane;
        float w = 1.0f;
        int off = 0;
#pragma unroll
        for (int d = 0; d < 10; ++d) {
            int node = off + (l >> (10 - d));
            float p  = rowbuf[wave][node];
            int bit  = (l >> (9 - d)) & 1;
            w *= bit ? p : (1.0f - p);
            off += (1 << d);
        }
        acc += w * rowbuf[wave][NSPLIT + l];
    }
#pragma unroll
    for (int s = 32; s > 0; s >>= 1) acc += __shfl_down(acc, s, 64);
    if (lane == 0) out[b] = acc;
}

// ---------------- launcher ----------------
extern "C" void kernel_launch(void* const* d_in, const int* in_sizes, int n_in,
                              void* d_out, int out_size, void* d_ws, size_t ws_size,
                              hipStream_t stream) {
    const float* x      = (const float*)d_in[0];
    const float* Wsplit = (const float*)d_in[1];
    const float* bsplit = (const float*)d_in[2];
    const float* Wleaf  = (const float*)d_in[3];
    const float* bleaf  = (const float*)d_in[4];
    float* out          = (float*)d_out;

    char* ws = (char*)d_ws;
    __bf16* Ap = (__bf16*)ws;                                   // 64 MiB
    __bf16* Bp = (__bf16*)(ws + (size_t)GM * PK * 2);           // 8 MiB
    float*  S  = (float*)(ws + (size_t)GM * PK * 2 + (size_t)GN * PK * 2); // 128 MiB

    pack_A<<<(GM * DIM / 8) / 256, 256, 0, stream>>>(x, Ap);
    pack_B<<<(GN * DIM / 8) / 256, 256, 0, stream>>>(Wsplit, Wleaf, Bp);

    gemm_kernel<<<512, 512, 0, stream>>>(Ap, Bp, bsplit, bleaf, S);

    routing_kernel<<<GM / 4, 256, 0, stream>>>(S, out);
}